// Round 5
// baseline (324.130 us; speedup 1.0000x reference)
//
#include <hip/hip_runtime.h>

typedef __attribute__((ext_vector_type(8))) short short8;
typedef __attribute__((ext_vector_type(4))) float floatx4;

#define N_SVC  50000
#define N_NODE 20000
#define N_POD  100000
#define E_SVC  1600000
#define E_PN   100000
#define E_NP   100000
#define N_TOT  170000   // dst order: svc [0,50k), node [50k,70k), pod [70k,170k)
#define E_TOT  1800000
#define NB2    167      // ceil(170000/1024), bucket = unified_id >> 10
#define NBLK   256
#define PER_BLK 7032    // ceil(E_TOT/NBLK)
// padded dst layout for MFMA tiles (each type padded to x64 rows):
#define P_SVC_BASE  0
#define P_NODE_BASE 50048
#define P_POD_BASE  70080
#define P_TOT       170112
// aggregate work split: svc waves [0,50048) wave-per-row; node/pod 4 rows/wave
#define SVC_WAVES   50048
#define AGG_WAVES   80064   // 50048 + (170112-50048)/4
#define AGG_BLOCKS  20016   // AGG_WAVES/4
// src unified order (Xn, cnt_src): svc [0,50k), pod [50k,150k), node [150k,170k)

__device__ __forceinline__ unsigned short f2bf(float f) {
  union { float f; unsigned u; } v; v.f = f;
  unsigned r = v.u + 0x7FFFu + ((v.u >> 16) & 1u);   // RNE
  return (unsigned short)(r >> 16);
}
__device__ __forceinline__ unsigned pack_bf2(float a, float b) {
  return (unsigned)f2bf(a) | ((unsigned)f2bf(b) << 16);
}
__device__ __forceinline__ float bfl(unsigned u) { union { unsigned u; float f; } v; v.u = u << 16; return v.f; }
__device__ __forceinline__ float bfh(unsigned u) { union { unsigned u; float f; } v; v.u = u & 0xFFFF0000u; return v.f; }

// ---- 1024-row bucket capacity layout (>= mean + 30 sigma for this graph size)
// dst: svc-ish b<49 cap 38400 | node-ish 49<=b<69 cap 7424 | pod-ish b>=69 cap 2048
__device__ __forceinline__ int dbase2(int b) {
  if (b < 49) return b * 38400;
  if (b < 69) return 1881600 + (b - 49) * 7424;
  return 2030080 + (b - 69) * 2048;
}
#define DST2_TOT 2230784
// src: svc b<49 cap 38400 | pod 49<=b<146 cap 2048 | node b>=146 cap 7424
__device__ __forceinline__ int sbase2(int b) {
  if (b < 49) return b * 38400;
  if (b < 146) return 1881600 + (b - 49) * 2048;
  return 2080256 + (b - 146) * 7424;
}
#define SRC2_TOT 2236160

// unified-id edge loader: src order svc/pod/node, dst order svc/node/pod
__device__ __forceinline__ void load_edge(int i,
    const int* __restrict__ svcS, const int* __restrict__ svcD,
    const int* __restrict__ pnS, const int* __restrict__ pnD,
    const int* __restrict__ npS, const int* __restrict__ npD,
    int& S, int& D) {
  if (i < E_SVC)             { S = svcS[i];                         D = svcD[i]; }
  else if (i < E_SVC + E_PN) { int j = i - E_SVC;        S = pnS[j] + 50000;  D = pnD[j] + 50000; }
  else                       { int j = i - E_SVC - E_PN; S = npS[j] + 150000; D = npD[j] + 70000; }
}

// ---------------- single-pass partition: edges in regs, LDS hist, reserve, scatter
// NOTE (measured r1): direct global atomicAdd for src degrees is memory-side on
// MI355X (65 MB write-back, 90 us) -- all per-edge atomics stay in LDS.
// NOTE (r5): 1024-row buckets -> per-block-per-bucket runs ~42 edges = 168 B,
// so dstbuf/srcbuf writes are mostly full 64B lines (128-row buckets gave 21 B
// sub-line bursts). dcur/scur hold relative counts (memset 0); bases added here.
__global__ __launch_bounds__(1024) void scatter_onepass(
    const int* __restrict__ svcS, const int* __restrict__ svcD,
    const int* __restrict__ pnS, const int* __restrict__ pnD,
    const int* __restrict__ npS, const int* __restrict__ npD,
    int* __restrict__ dcur, int* __restrict__ scur,
    unsigned* __restrict__ dstbuf, unsigned short* __restrict__ srcbuf) {
  __shared__ int ldc[NB2], lsc[NB2];
  const int tid = threadIdx.x;
  if (tid < NB2) { ldc[tid] = 0; lsc[tid] = 0; }
  __syncthreads();
  const int lo = blockIdx.x * PER_BLK;
  const int hi = (lo + PER_BLK < E_TOT) ? lo + PER_BLK : E_TOT;
  int Sv[7], Dv[7];
  #pragma unroll
  for (int k = 0; k < 7; ++k) {
    int e = lo + tid + k * 1024;
    if (e < hi) {
      load_edge(e, svcS, svcD, pnS, pnD, npS, npD, Sv[k], Dv[k]);
      atomicAdd(&ldc[Dv[k] >> 10], 1);
      atomicAdd(&lsc[Sv[k] >> 10], 1);
    } else Sv[k] = -1;
  }
  __syncthreads();
  if (tid < NB2) {
    int c = ldc[tid];  ldc[tid] = c ? (dbase2(tid) + atomicAdd(&dcur[tid], c)) : 0;
    int c2 = lsc[tid]; lsc[tid] = c2 ? (sbase2(tid) + atomicAdd(&scur[tid], c2)) : 0;
  }
  __syncthreads();
  #pragma unroll
  for (int k = 0; k < 7; ++k) {
    if (Sv[k] >= 0) {
      int p = atomicAdd(&ldc[Dv[k] >> 10], 1);
      dstbuf[p] = ((unsigned)(Dv[k] & 1023) << 18) | (unsigned)Sv[k];
      int q = atomicAdd(&lsc[Sv[k] >> 10], 1);
      srcbuf[q] = (unsigned short)(Sv[k] & 1023);
    }
  }
}

// ---------------- finalize: dst CSR + rowrange (blocks [0,NB2)), src counts (rest)
// 512 threads, 1024-counter LDS hist, 2-level scan (2 counters/thread).
__global__ __launch_bounds__(512) void finalize_all(
    const int* __restrict__ dcur, const int* __restrict__ scur,
    const unsigned* __restrict__ dstbuf, const unsigned short* __restrict__ srcbuf,
    int2* __restrict__ rowrange, int* __restrict__ csr, int* __restrict__ cnt_src) {
  __shared__ int lcnt[1024], lcur[1024];
  __shared__ int wsum[8], woff[8];
  const int tid = threadIdx.x;
  const int w = tid >> 6, lane = tid & 63;
  if (blockIdx.x < NB2) {
    const int b = blockIdx.x;
    const int base = dbase2(b);
    const int cnt = dcur[b];
    lcnt[2 * tid] = 0; lcnt[2 * tid + 1] = 0;
    __syncthreads();
    for (int e = tid; e < cnt; e += 512) atomicAdd(&lcnt[dstbuf[base + e] >> 18], 1);
    __syncthreads();
    int v0 = lcnt[2 * tid], v1 = lcnt[2 * tid + 1];
    int s = v0 + v1;
    int x = s;
    #pragma unroll
    for (int off = 1; off < 64; off <<= 1) {
      int y = __shfl_up(x, off, 64);
      if (lane >= off) x += y;
    }
    if (lane == 63) wsum[w] = x;
    __syncthreads();
    if (tid == 0) {
      int acc = 0;
      #pragma unroll
      for (int i = 0; i < 8; i++) { woff[i] = acc; acc += wsum[i]; }
    }
    __syncthreads();
    int excl = x - s + woff[w];
    lcur[2 * tid] = excl;
    lcur[2 * tid + 1] = excl + v0;
    int u0 = b * 1024 + 2 * tid;
    if (u0 < N_TOT)     rowrange[u0]     = make_int2(base + excl, base + excl + v0);
    if (u0 + 1 < N_TOT) rowrange[u0 + 1] = make_int2(base + excl + v0, base + excl + v0 + v1);
    __syncthreads();
    for (int e = tid; e < cnt; e += 512) {
      unsigned wv = dstbuf[base + e];
      int p = atomicAdd(&lcur[wv >> 18], 1);
      csr[base + p] = (int)(wv & 0x3FFFFu);
    }
  } else {
    const int b = blockIdx.x - NB2;
    const int base = sbase2(b);
    const int cnt = scur[b];
    lcnt[2 * tid] = 0; lcnt[2 * tid + 1] = 0;
    __syncthreads();
    for (int e = tid; e < cnt; e += 512) atomicAdd(&lcnt[srcbuf[base + e]], 1);
    __syncthreads();
    int u0 = b * 1024 + 2 * tid;
    if (u0 < N_TOT)     cnt_src[u0]     = lcnt[2 * tid];
    if (u0 + 1 < N_TOT) cnt_src[u0 + 1] = lcnt[2 * tid + 1];
  }
}

// --------------------------- normalize by rsqrt(deg_src) and cast to bf16
// 16 B/thread: each thread handles 4 consecutive pairs (one float4).
__global__ void normalize_cast(const float* __restrict__ xs, const float* __restrict__ xp,
                               const float* __restrict__ xn, const int* __restrict__ cs,
                               unsigned* __restrict__ Xn) {
  int i = blockIdx.x * blockDim.x + threadIdx.x;   // quad id
  if (i >= N_TOT * 32) return;
  int row = i >> 5, c4 = i & 31;
  const float* src;
  if (row < 50000)       src = xs + (size_t)row * 128;
  else if (row < 150000) src = xp + (size_t)(row - 50000) * 128;
  else                   src = xn + (size_t)(row - 150000) * 128;
  int cc = cs[row]; if (cc < 1) cc = 1;
  float r = rsqrtf((float)cc);
  float4 v = ((const float4*)src)[c4];
  uint2 o;
  o.x = pack_bf2(v.x * r, v.y * r);
  o.y = pack_bf2(v.z * r, v.w * r);
  *(uint2*)(Xn + (size_t)row * 64 + c4 * 2) = o;
}

#define ACC8(v) { a0 += bfl(v.x); a1 += bfh(v.x); a2 += bfl(v.y); a3 += bfh(v.y); \
                  a4 += bfl(v.z); a5 += bfh(v.z); a6 += bfl(v.w); a7 += bfh(v.w); }

// ------------------ aggregation, degree-adaptive (r4-proven, unchanged):
//   svc rows: wave-per-row, 4 edge-slots x 16 lanes, 16-edge unroll.
//   node/pod rows: one 16-lane group per row, 4 rows/wave.
__global__ __launch_bounds__(256) void aggregate_bf16(
    const unsigned* __restrict__ Xn, const int2* __restrict__ rowrange,
    const int* __restrict__ csr, unsigned* __restrict__ aggb) {
  const int lane = threadIdx.x & 63;
  const int gwave = blockIdx.x * 4 + (threadIdx.x >> 6);
  const int grp = lane >> 4, l16 = lane & 15;
  const unsigned* Xb = Xn + l16 * 4;
  if (gwave < SVC_WAVES) {
    // ---- svc: wave-per-row, 4 edge-slots
    const int gw = gwave;
    unsigned* orow = aggb + (size_t)gw * 64 + l16 * 4;
    if (gw >= 50000) {
      if (grp == 0) *(uint4*)orow = (uint4){0u, 0u, 0u, 0u};
      return;
    }
    int2 rr = rowrange[gw];
    int beg = rr.x, end = rr.y;
    int deg = end - beg;
    float a0 = 0.f, a1 = 0.f, a2 = 0.f, a3 = 0.f, a4 = 0.f, a5 = 0.f, a6 = 0.f, a7 = 0.f;
    int e = beg;
    for (; e + 16 <= end; e += 16) {
      int sA = csr[e + grp];
      int sB = csr[e + 4 + grp];
      int sC = csr[e + 8 + grp];
      int sD = csr[e + 12 + grp];
      uint4 vA = *(const uint4*)(Xb + (unsigned)sA * 64);
      uint4 vB = *(const uint4*)(Xb + (unsigned)sB * 64);
      uint4 vC = *(const uint4*)(Xb + (unsigned)sC * 64);
      uint4 vD = *(const uint4*)(Xb + (unsigned)sD * 64);
      ACC8(vA) ACC8(vB) ACC8(vC) ACC8(vD)
    }
    for (; e + 8 <= end; e += 8) {
      int sA = csr[e + grp];
      int sB = csr[e + 4 + grp];
      uint4 vA = *(const uint4*)(Xb + (unsigned)sA * 64);
      uint4 vB = *(const uint4*)(Xb + (unsigned)sB * 64);
      ACC8(vA) ACC8(vB)
    }
    for (; e + 4 <= end; e += 4) {
      int s = csr[e + grp];
      uint4 v = *(const uint4*)(Xb + (unsigned)s * 64);
      ACC8(v)
    }
    if (grp < end - e) {
      int s = csr[e + grp];
      uint4 v = *(const uint4*)(Xb + (unsigned)s * 64);
      ACC8(v)
    }
    // reduce across the 4 edge-slots (lanes l, l+16, l+32, l+48)
    a0 += __shfl_xor(a0, 32, 64); a1 += __shfl_xor(a1, 32, 64);
    a2 += __shfl_xor(a2, 32, 64); a3 += __shfl_xor(a3, 32, 64);
    a4 += __shfl_xor(a4, 32, 64); a5 += __shfl_xor(a5, 32, 64);
    a6 += __shfl_xor(a6, 32, 64); a7 += __shfl_xor(a7, 32, 64);
    a0 += __shfl_xor(a0, 16, 64); a1 += __shfl_xor(a1, 16, 64);
    a2 += __shfl_xor(a2, 16, 64); a3 += __shfl_xor(a3, 16, 64);
    a4 += __shfl_xor(a4, 16, 64); a5 += __shfl_xor(a5, 16, 64);
    a6 += __shfl_xor(a6, 16, 64); a7 += __shfl_xor(a7, 16, 64);
    float rd = rsqrtf((float)(deg < 1 ? 1 : deg));
    if (grp == 0) {
      uint4 o;
      o.x = pack_bf2(a0 * rd, a1 * rd);
      o.y = pack_bf2(a2 * rd, a3 * rd);
      o.z = pack_bf2(a4 * rd, a5 * rd);
      o.w = pack_bf2(a6 * rd, a7 * rd);
      *(uint4*)orow = o;
    }
  } else {
    // ---- node/pod: 16-lane group per row, 4 rows per wave
    const int row = SVC_WAVES + (gwave - SVC_WAVES) * 4 + grp;   // padded row id
    int u; bool valid;
    if (row < P_POD_BASE) { u = row - 48; valid = (row - P_NODE_BASE) < 20000; }
    else                  { u = row - 80; valid = (row - P_POD_BASE) < 100000; }
    unsigned* orow = aggb + (size_t)row * 64 + l16 * 4;
    if (!valid) {
      *(uint4*)orow = (uint4){0u, 0u, 0u, 0u};
      return;
    }
    int2 rr = rowrange[u];
    int beg = rr.x, end = rr.y;
    int deg = end - beg;
    float a0 = 0.f, a1 = 0.f, a2 = 0.f, a3 = 0.f, a4 = 0.f, a5 = 0.f, a6 = 0.f, a7 = 0.f;
    int e = beg;
    for (; e + 2 <= end; e += 2) {
      int s0 = csr[e];
      int s1 = csr[e + 1];
      uint4 v0 = *(const uint4*)(Xb + (unsigned)s0 * 64);
      uint4 v1 = *(const uint4*)(Xb + (unsigned)s1 * 64);
      ACC8(v0) ACC8(v1)
    }
    if (e < end) {
      int s = csr[e];
      uint4 v = *(const uint4*)(Xb + (unsigned)s * 64);
      ACC8(v)
    }
    float rd = rsqrtf((float)(deg < 1 ? 1 : deg));
    uint4 o;
    o.x = pack_bf2(a0 * rd, a1 * rd);
    o.y = pack_bf2(a2 * rd, a3 * rd);
    o.z = pack_bf2(a4 * rd, a5 * rd);
    o.w = pack_bf2(a6 * rd, a7 * rd);
    *(uint4*)orow = o;
  }
}

// ------------------------- transpose + cast weights to bf16 (tiny, once)
__global__ void wprep(const float* __restrict__ W0, const float* __restrict__ W1,
                      const float* __restrict__ W2, const float* __restrict__ L0,
                      const float* __restrict__ L1, const float* __restrict__ L2,
                      unsigned short* __restrict__ Wt, unsigned short* __restrict__ Wt2) {
  int i = blockIdx.x * 256 + threadIdx.x;
  if (i < 3 * 16384) {
    int t = i / 16384, r = i % 16384, n = r / 128, k = r % 128;
    const float* W = (t == 0) ? W0 : ((t == 1) ? W1 : W2);
    Wt[i] = f2bf(W[k * 128 + n]);           // Wt[t][n][k] = W[k][n]
  } else if (i < 3 * 16384 + 3 * 8192) {
    int j = i - 3 * 16384;
    int t = j / 8192, r = j % 8192, n = r / 128, k = r % 128;
    const float* L = (t == 0) ? L0 : ((t == 1) ? L1 : L2);
    Wt2[j] = f2bf(L[k * 64 + n]);           // Wt2[t][n][k] = Wl[k][n]
  }
}

// ---- fused MFMA GEMM, persistent blocks: O = (leaky(A@W+b))@Wl + bl
__global__ __launch_bounds__(256) void gemm_fused(
    const unsigned short* __restrict__ aggb,
    const unsigned short* __restrict__ Wt,   // 3 x [128 x 128] (n-major)
    const unsigned short* __restrict__ Wt2,  // 3 x [64 x 128]  (n-major)
    const float* __restrict__ b0, const float* __restrict__ b1, const float* __restrict__ b2,
    const float* __restrict__ l0, const float* __restrict__ l1, const float* __restrict__ l2,
    float* __restrict__ out) {
  __shared__ __align__(16) unsigned short sW1[128 * 136];   // 34816 B
  __shared__ __align__(16) unsigned short sH[4][16 * 136];  // 17408 B (per-wave)
  const int bid = blockIdx.x;
  int t, bl, nb, ntile, padbase, outbase, mcnt;
  if (bid < 226)      { t = 0; bl = bid;       nb = 226; ntile = 782;  padbase = P_SVC_BASE;  outbase = 0;     mcnt = 50000; }
  else if (bid < 316) { t = 1; bl = bid - 226; nb = 90;  ntile = 313;  padbase = P_NODE_BASE; outbase = 50000; mcnt = 20000; }
  else                { t = 2; bl = bid - 316; nb = 452; ntile = 1563; padbase = P_POD_BASE;  outbase = 70000; mcnt = 100000; }
  const float* bp = (t == 0) ? b0 : ((t == 1) ? b1 : b2);
  const float* lp = (t == 0) ? l0 : ((t == 1) ? l1 : l2);

  // stage W1 into LDS (2048 x 16B units)
  const unsigned short* W1g = Wt + t * 16384;
  for (int uu = threadIdx.x; uu < 2048; uu += 256) {
    short8 v = *(const short8*)(W1g + uu * 8);
    *(short8*)(&sW1[(uu >> 4) * 136 + (uu & 15) * 8]) = v;
  }
  const int wv = threadIdx.x >> 6, lane = threadIdx.x & 63;
  const int quad = lane >> 4, l16 = lane & 15;

  // W2 fragments + biases in registers (per lane)
  const unsigned short* W2g = Wt2 + t * 8192;
  short8 w2f[4][4];
  #pragma unroll
  for (int n = 0; n < 4; n++)
    #pragma unroll
    for (int kt = 0; kt < 4; kt++)
      w2f[n][kt] = *(const short8*)(W2g + (n * 16 + l16) * 128 + kt * 32 + quad * 8);
  float bias1[8], bias2[4];
  #pragma unroll
  for (int n = 0; n < 8; n++) bias1[n] = bp[n * 16 + l16];
  #pragma unroll
  for (int n = 0; n < 4; n++) bias2[n] = lp[n * 16 + l16];
  __syncthreads();

  for (int tile = bl; tile < ntile; tile += nb) {
    const unsigned short* Arow = aggb + (size_t)(padbase + tile * 64 + wv * 16 + l16) * 128;
    floatx4 acc[8];
    #pragma unroll
    for (int n = 0; n < 8; n++) acc[n] = (floatx4){0.f, 0.f, 0.f, 0.f};
    #pragma unroll
    for (int kt = 0; kt < 4; kt++) {
      short8 af = *(const short8*)(Arow + kt * 32 + quad * 8);
      #pragma unroll
      for (int n = 0; n < 8; n++) {
        short8 bf = *(const short8*)(&sW1[(n * 16 + l16) * 136 + kt * 32 + quad * 8]);
        acc[n] = __builtin_amdgcn_mfma_f32_16x16x32_bf16(af, bf, acc[n], 0, 0, 0);
      }
    }
    // bias + leaky, C-layout -> per-wave LDS tile (row-major, stride 136)
    #pragma unroll
    for (int n = 0; n < 8; n++) {
      #pragma unroll
      for (int i = 0; i < 4; i++) {
        float h = acc[n][i] + bias1[n];
        h = (h > 0.f) ? h : 0.01f * h;
        sH[wv][(quad * 4 + i) * 136 + n * 16 + l16] = f2bf(h);
      }
    }
    // GEMM2 from per-wave LDS (intra-wave dep; compiler orders via lgkmcnt)
    floatx4 acc2[4];
    #pragma unroll
    for (int n = 0; n < 4; n++) acc2[n] = (floatx4){0.f, 0.f, 0.f, 0.f};
    #pragma unroll
    for (int kt = 0; kt < 4; kt++) {
      short8 af = *(const short8*)(&sH[wv][l16 * 136 + kt * 32 + quad * 8]);
      #pragma unroll
      for (int n = 0; n < 4; n++)
        acc2[n] = __builtin_amdgcn_mfma_f32_16x16x32_bf16(af, w2f[n][kt], acc2[n], 0, 0, 0);
    }
    int r0 = tile * 64 + wv * 16 + quad * 4;   // type-local row
    #pragma unroll
    for (int n = 0; n < 4; n++) {
      #pragma unroll
      for (int i = 0; i < 4; i++) {
        int r = r0 + i;
        if (r < mcnt) out[(size_t)(outbase + r) * 64 + n * 16 + l16] = acc2[n][i] + bias2[n];
      }
    }
  }
}

extern "C" void kernel_launch(void* const* d_in, const int* in_sizes, int n_in,
                              void* d_out, int out_size, void* d_ws, size_t ws_size,
                              hipStream_t stream) {
  const float* x_svc  = (const float*)d_in[0];
  const float* x_pod  = (const float*)d_in[1];
  const float* x_node = (const float*)d_in[2];
  const int* svc_src  = (const int*)d_in[3];
  const int* svc_dst  = (const int*)d_in[4];
  const int* pn_src   = (const int*)d_in[5];
  const int* pn_dst   = (const int*)d_in[6];
  const int* np_src   = (const int*)d_in[7];
  const int* np_dst   = (const int*)d_in[8];
  const float* W_call = (const float*)d_in[9];
  const float* b_call = (const float*)d_in[10];
  const float* W_in   = (const float*)d_in[11];
  const float* b_in   = (const float*)d_in[12];
  const float* W_ni   = (const float*)d_in[13];
  const float* b_ni   = (const float*)d_in[14];
  const float* W_ls   = (const float*)d_in[15];
  const float* b_ls   = (const float*)d_in[16];
  const float* W_ln   = (const float*)d_in[17];
  const float* b_ln   = (const float*)d_in[18];
  const float* W_lp   = (const float*)d_in[19];
  const float* b_lp   = (const float*)d_in[20];
  float* out = (float*)d_out;

  // workspace layout (lifetimes):
  //   dcur     @ 0        (668 B)   \ one memset covers both
  //   scur     @ 668      (668 B)   /
  //   rowrange @ 1344     (170000 int2 -> ends 1361344)
  //   cnt_src  @ 1361344  (170000 int  -> ends 2041344)
  //   csr      @ 2041344  (DST2_TOT ints = 8.92 MB -> ends 10964480)
  //   Wt       @ 10964480 (98304 B -> ends 11062784)
  //   Wt2      @ 11062784 (49152 B -> ends 11111936)
  //   Xn       @ 11112448 (43.55 MB -> ends 54661120)
  //   dstbuf   @ 11112448 (8.92 MB, aliases Xn: dead before normalize writes Xn)
  //   srcbuf   @ 20040192 (4.47 MB, aliases Xn: dead before normalize)
  //   aggb     @ 54661120 (43.55 MB -> ends 98209792)
  char* ws = (char*)d_ws;
  int*  dcur     = (int*)(ws + 0);
  int*  scur     = (int*)(ws + 668);
  int2* rowrange = (int2*)(ws + 1344);
  int*  cnt_src  = (int*)(ws + 1361344);
  int*  csr      = (int*)(ws + 2041344);
  unsigned short* Wt  = (unsigned short*)(ws + 10964480);
  unsigned short* Wt2 = (unsigned short*)(ws + 11062784);
  unsigned* Xn     = (unsigned*)(ws + 11112448);
  unsigned* dstbuf = (unsigned*)(ws + 11112448);
  unsigned short* srcbuf = (unsigned short*)(ws + 20040192);
  unsigned* aggb   = (unsigned*)(ws + 54661120);

  hipMemsetAsync(dcur, 0, 1336, stream);   // dcur + scur (relative counts)
  scatter_onepass<<<NBLK, 1024, 0, stream>>>(svc_src, svc_dst, pn_src, pn_dst,
                                             np_src, np_dst, dcur, scur, dstbuf, srcbuf);
  finalize_all<<<2 * NB2, 512, 0, stream>>>(dcur, scur, dstbuf, srcbuf,
                                            rowrange, csr, cnt_src);
  wprep<<<288, 256, 0, stream>>>(W_call, W_in, W_ni, W_ls, W_ln, W_lp, Wt, Wt2);
  normalize_cast<<<21250, 256, 0, stream>>>(x_svc, x_pod, x_node, cnt_src, Xn);
  aggregate_bf16<<<AGG_BLOCKS, 256, 0, stream>>>(Xn, rowrange, csr, aggb);
  gemm_fused<<<768, 256, 0, stream>>>((const unsigned short*)aggb, Wt, Wt2,
                                      b_call, b_in, b_ni, b_ls, b_ln, b_lp, out);
}

// Round 6
// 313.762 us; speedup vs baseline: 1.0330x; 1.0330x over previous
//
#include <hip/hip_runtime.h>

typedef __attribute__((ext_vector_type(8))) short short8;
typedef __attribute__((ext_vector_type(4))) float floatx4;

#define N_SVC  50000
#define N_NODE 20000
#define N_POD  100000
#define E_SVC  1600000
#define E_PN   100000
#define E_NP   100000
#define N_TOT  170000   // dst order: svc [0,50k), node [50k,70k), pod [70k,170k)
#define E_TOT  1800000
#define NBUCK  1329     // ceil(170000/128), bucket = unified_id >> 7
#define NBLK   256
#define PER_BLK 7032    // ceil(E_TOT/NBLK)
// padded dst layout for MFMA tiles (each type padded to x64 rows):
#define P_SVC_BASE  0
#define P_NODE_BASE 50048
#define P_POD_BASE  70080
#define P_TOT       170112
// aggregate split: svc = wave-per-row (50048 waves); node/pod = 4 rows/wave
#define SVC_WAVES   50048
#define SVC_BLOCKS  12512   // SVC_WAVES/4
#define NP_WAVES    30016   // (P_TOT - SVC_WAVES)/4
#define NP_BLOCKS   7504    // NP_WAVES/4
// src unified order (Xn, cnt_src): svc [0,50k), pod [50k,150k), node [150k,170k)

__device__ __forceinline__ unsigned short f2bf(float f) {
  union { float f; unsigned u; } v; v.f = f;
  unsigned r = v.u + 0x7FFFu + ((v.u >> 16) & 1u);   // RNE
  return (unsigned short)(r >> 16);
}
__device__ __forceinline__ unsigned pack_bf2(float a, float b) {
  return (unsigned)f2bf(a) | ((unsigned)f2bf(b) << 16);
}
__device__ __forceinline__ float bfl(unsigned u) { union { unsigned u; float f; } v; v.u = u << 16; return v.f; }
__device__ __forceinline__ float bfh(unsigned u) { union { unsigned u; float f; } v; v.u = u & 0xFFFF0000u; return v.f; }

// static bucket capacity layout (over-provisioned >= mean + 30 sigma)
// NOTE (measured r5): coarser 1024-row buckets REGRESSED (~+16 us): 167-counter
// LDS hist has 8x atomic contention, and 334-block finalize is imbalance-bound
// (49 buckets x ~33k edges set the critical path). 128-row buckets are the
// measured sweet spot.
// dst buckets: svc [0,391] cap 6144 | node (391,547] cap 1536 | pod (547,1328] cap 512
__device__ __forceinline__ int dbase_of(int b) {
  if (b <= 391) return b * 6144;
  if (b <= 547) return 2402304 + (b - 391) * 1536;
  return 2641920 + (b - 547) * 512;
}
#define DST_CAP_TOT 3042304
// src buckets: svc [0,391] cap 6144 | pod (391,1171] cap 512 | node (1171,1328] cap 1536
__device__ __forceinline__ int sbase_of(int b) {
  if (b <= 391) return b * 6144;
  if (b <= 1171) return 2402304 + (b - 391) * 512;
  return 2801664 + (b - 1171) * 1536;
}
#define SRC_CAP_TOT 3044352

// unified-id edge loader: src order svc/pod/node, dst order svc/node/pod
__device__ __forceinline__ void load_edge(int i,
    const int* __restrict__ svcS, const int* __restrict__ svcD,
    const int* __restrict__ pnS, const int* __restrict__ pnD,
    const int* __restrict__ npS, const int* __restrict__ npD,
    int& S, int& D) {
  if (i < E_SVC)             { S = svcS[i];                         D = svcD[i]; }
  else if (i < E_SVC + E_PN) { int j = i - E_SVC;        S = pnS[j] + 50000;  D = pnD[j] + 50000; }
  else                       { int j = i - E_SVC - E_PN; S = npS[j] + 150000; D = npD[j] + 70000; }
}

// ---------------- cursor init to static bases
__global__ void init_cur(int* __restrict__ dcur, int* __restrict__ scur) {
  int b = blockIdx.x * 1024 + threadIdx.x;
  if (b < NBUCK) { dcur[b] = dbase_of(b); scur[b] = sbase_of(b); }
}

// ---------------- single-pass partition: edges in regs, LDS hist, reserve, scatter
// NOTE (measured r1): direct global atomicAdd for src degrees is memory-side on
// MI355X (65 MB write-back, 90 us) -- all per-edge atomics stay in LDS.
__global__ __launch_bounds__(1024) void scatter_onepass(
    const int* __restrict__ svcS, const int* __restrict__ svcD,
    const int* __restrict__ pnS, const int* __restrict__ pnD,
    const int* __restrict__ npS, const int* __restrict__ npD,
    int* __restrict__ dcur, int* __restrict__ scur,
    unsigned* __restrict__ dstbuf, unsigned char* __restrict__ srcbuf) {
  __shared__ int ldc[NBUCK], lsc[NBUCK];
  const int tid = threadIdx.x;
  for (int t = tid; t < NBUCK; t += 1024) { ldc[t] = 0; lsc[t] = 0; }
  __syncthreads();
  const int lo = blockIdx.x * PER_BLK;
  const int hi = (lo + PER_BLK < E_TOT) ? lo + PER_BLK : E_TOT;
  int Sv[7], Dv[7];
  #pragma unroll
  for (int k = 0; k < 7; ++k) {
    int e = lo + tid + k * 1024;
    if (e < hi) {
      load_edge(e, svcS, svcD, pnS, pnD, npS, npD, Sv[k], Dv[k]);
      atomicAdd(&ldc[Dv[k] >> 7], 1);
      atomicAdd(&lsc[Sv[k] >> 7], 1);
    } else Sv[k] = -1;
  }
  __syncthreads();
  for (int t = tid; t < NBUCK; t += 1024) {
    int c = ldc[t];  ldc[t] = c ? atomicAdd(&dcur[t], c) : 0;
    int c2 = lsc[t]; lsc[t] = c2 ? atomicAdd(&scur[t], c2) : 0;
  }
  __syncthreads();
  #pragma unroll
  for (int k = 0; k < 7; ++k) {
    if (Sv[k] >= 0) {
      int p = atomicAdd(&ldc[Dv[k] >> 7], 1);
      dstbuf[p] = ((unsigned)(Dv[k] & 127) << 18) | (unsigned)Sv[k];
      int q = atomicAdd(&lsc[Sv[k] >> 7], 1);
      srcbuf[q] = (unsigned char)(Sv[k] & 127);
    }
  }
}

// ---------------- finalize: dst CSR + rowrange (blocks [0,NBUCK)), src counts (rest)
__global__ __launch_bounds__(256) void finalize_all(
    const int* __restrict__ dcur, const int* __restrict__ scur,
    const unsigned* __restrict__ dstbuf, const unsigned char* __restrict__ srcbuf,
    int2* __restrict__ rowrange, int* __restrict__ csr, int* __restrict__ cnt_src) {
  __shared__ int lcnt[128], lcur[128];
  __shared__ int s_w0;
  const int tid = threadIdx.x;
  if (blockIdx.x < NBUCK) {
    const int b = blockIdx.x;
    const int base = dbase_of(b);
    const int cnt = dcur[b] - base;
    if (tid < 128) lcnt[tid] = 0;
    __syncthreads();
    for (int e = tid; e < cnt; e += 256) atomicAdd(&lcnt[dstbuf[base + e] >> 18], 1);
    __syncthreads();
    int excl = 0, v = 0;
    if (tid < 128) {
      v = lcnt[tid];
      int lane = tid & 63;
      int x = v;
      #pragma unroll
      for (int off = 1; off < 64; off <<= 1) {
        int y = __shfl_up(x, off, 64);
        if (lane >= off) x += y;
      }
      excl = x - v;
      if (tid == 63) s_w0 = x;
    }
    __syncthreads();
    if (tid < 128) {
      if (tid >= 64) excl += s_w0;
      lcur[tid] = excl;
      int u = b * 128 + tid;
      if (u < N_TOT) rowrange[u] = make_int2(base + excl, base + excl + v);
    }
    __syncthreads();
    for (int e = tid; e < cnt; e += 256) {
      unsigned wv = dstbuf[base + e];
      int p = atomicAdd(&lcur[wv >> 18], 1);
      csr[base + p] = (int)(wv & 0x3FFFFu);
    }
  } else {
    const int b = blockIdx.x - NBUCK;
    const int base = sbase_of(b);
    const int cnt = scur[b] - base;
    if (tid < 128) lcnt[tid] = 0;
    __syncthreads();
    for (int e = tid; e < cnt; e += 256) atomicAdd(&lcnt[srcbuf[base + e]], 1);
    __syncthreads();
    if (tid < 128) {
      int u = b * 128 + tid;
      if (u < N_TOT) cnt_src[u] = lcnt[tid];
    }
  }
}

// --------------------------- normalize by rsqrt(deg_src) and cast to bf16
// 16 B/thread: each thread handles 4 consecutive pairs (one float4).
__global__ void normalize_cast(const float* __restrict__ xs, const float* __restrict__ xp,
                               const float* __restrict__ xn, const int* __restrict__ cs,
                               unsigned* __restrict__ Xn) {
  int i = blockIdx.x * blockDim.x + threadIdx.x;   // quad id
  if (i >= N_TOT * 32) return;
  int row = i >> 5, c4 = i & 31;
  const float* src;
  if (row < 50000)       src = xs + (size_t)row * 128;
  else if (row < 150000) src = xp + (size_t)(row - 50000) * 128;
  else                   src = xn + (size_t)(row - 150000) * 128;
  int cc = cs[row]; if (cc < 1) cc = 1;
  float r = rsqrtf((float)cc);
  float4 v = ((const float4*)src)[c4];
  uint2 o;
  o.x = pack_bf2(v.x * r, v.y * r);
  o.y = pack_bf2(v.z * r, v.w * r);
  *(uint2*)(Xn + (size_t)row * 64 + c4 * 2) = o;
}

#define ACC8(v) { a0 += bfl(v.x); a1 += bfh(v.x); a2 += bfl(v.y); a3 += bfh(v.y); \
                  a4 += bfl(v.z); a5 += bfh(v.z); a6 += bfl(v.w); a7 += bfh(v.w); }

// ------------------ aggregation, svc rows: wave-per-row, 4 edge-slots x 16
// lanes, 16-edge unroll (4 gathers in flight). Split from the np kernel so
// rocprof's top-5 window can see past it (it was pinning all 5 slots).
__global__ __launch_bounds__(256) void aggregate_svc(
    const unsigned* __restrict__ Xn, const int2* __restrict__ rowrange,
    const int* __restrict__ csr, unsigned* __restrict__ aggb) {
  const int lane = threadIdx.x & 63;
  const int gw = blockIdx.x * 4 + (threadIdx.x >> 6);
  const int grp = lane >> 4, l16 = lane & 15;
  const unsigned* Xb = Xn + l16 * 4;
  unsigned* orow = aggb + (size_t)gw * 64 + l16 * 4;
  if (gw >= 50000) {
    if (gw < SVC_WAVES && grp == 0) *(uint4*)orow = (uint4){0u, 0u, 0u, 0u};
    return;
  }
  int2 rr = rowrange[gw];
  int beg = rr.x, end = rr.y;
  int deg = end - beg;
  float a0 = 0.f, a1 = 0.f, a2 = 0.f, a3 = 0.f, a4 = 0.f, a5 = 0.f, a6 = 0.f, a7 = 0.f;
  int e = beg;
  for (; e + 16 <= end; e += 16) {
    int sA = csr[e + grp];
    int sB = csr[e + 4 + grp];
    int sC = csr[e + 8 + grp];
    int sD = csr[e + 12 + grp];
    uint4 vA = *(const uint4*)(Xb + (unsigned)sA * 64);
    uint4 vB = *(const uint4*)(Xb + (unsigned)sB * 64);
    uint4 vC = *(const uint4*)(Xb + (unsigned)sC * 64);
    uint4 vD = *(const uint4*)(Xb + (unsigned)sD * 64);
    ACC8(vA) ACC8(vB) ACC8(vC) ACC8(vD)
  }
  for (; e + 8 <= end; e += 8) {
    int sA = csr[e + grp];
    int sB = csr[e + 4 + grp];
    uint4 vA = *(const uint4*)(Xb + (unsigned)sA * 64);
    uint4 vB = *(const uint4*)(Xb + (unsigned)sB * 64);
    ACC8(vA) ACC8(vB)
  }
  for (; e + 4 <= end; e += 4) {
    int s = csr[e + grp];
    uint4 v = *(const uint4*)(Xb + (unsigned)s * 64);
    ACC8(v)
  }
  if (grp < end - e) {
    int s = csr[e + grp];
    uint4 v = *(const uint4*)(Xb + (unsigned)s * 64);
    ACC8(v)
  }
  // reduce across the 4 edge-slots (lanes l, l+16, l+32, l+48)
  a0 += __shfl_xor(a0, 32, 64); a1 += __shfl_xor(a1, 32, 64);
  a2 += __shfl_xor(a2, 32, 64); a3 += __shfl_xor(a3, 32, 64);
  a4 += __shfl_xor(a4, 32, 64); a5 += __shfl_xor(a5, 32, 64);
  a6 += __shfl_xor(a6, 32, 64); a7 += __shfl_xor(a7, 32, 64);
  a0 += __shfl_xor(a0, 16, 64); a1 += __shfl_xor(a1, 16, 64);
  a2 += __shfl_xor(a2, 16, 64); a3 += __shfl_xor(a3, 16, 64);
  a4 += __shfl_xor(a4, 16, 64); a5 += __shfl_xor(a5, 16, 64);
  a6 += __shfl_xor(a6, 16, 64); a7 += __shfl_xor(a7, 16, 64);
  float rd = rsqrtf((float)(deg < 1 ? 1 : deg));
  if (grp == 0) {
    uint4 o;
    o.x = pack_bf2(a0 * rd, a1 * rd);
    o.y = pack_bf2(a2 * rd, a3 * rd);
    o.z = pack_bf2(a4 * rd, a5 * rd);
    o.w = pack_bf2(a6 * rd, a7 * rd);
    *(uint4*)orow = o;
  }
}

// ------------------ aggregation, node/pod rows (mean deg 5 / 1):
// one 16-lane group per row, 4 rows per wave.
__global__ __launch_bounds__(256) void aggregate_np(
    const unsigned* __restrict__ Xn, const int2* __restrict__ rowrange,
    const int* __restrict__ csr, unsigned* __restrict__ aggb) {
  const int lane = threadIdx.x & 63;
  const int w = blockIdx.x * 4 + (threadIdx.x >> 6);
  const int grp = lane >> 4, l16 = lane & 15;
  const unsigned* Xb = Xn + l16 * 4;
  const int row = SVC_WAVES + w * 4 + grp;   // padded row id
  if (row >= P_TOT) return;
  int u; bool valid;
  if (row < P_POD_BASE) { u = row - 48; valid = (row - P_NODE_BASE) < 20000; }
  else                  { u = row - 80; valid = (row - P_POD_BASE) < 100000; }
  unsigned* orow = aggb + (size_t)row * 64 + l16 * 4;
  if (!valid) {
    *(uint4*)orow = (uint4){0u, 0u, 0u, 0u};
    return;
  }
  int2 rr = rowrange[u];
  int beg = rr.x, end = rr.y;
  int deg = end - beg;
  float a0 = 0.f, a1 = 0.f, a2 = 0.f, a3 = 0.f, a4 = 0.f, a5 = 0.f, a6 = 0.f, a7 = 0.f;
  int e = beg;
  for (; e + 2 <= end; e += 2) {
    int s0 = csr[e];
    int s1 = csr[e + 1];
    uint4 v0 = *(const uint4*)(Xb + (unsigned)s0 * 64);
    uint4 v1 = *(const uint4*)(Xb + (unsigned)s1 * 64);
    ACC8(v0) ACC8(v1)
  }
  if (e < end) {
    int s = csr[e];
    uint4 v = *(const uint4*)(Xb + (unsigned)s * 64);
    ACC8(v)
  }
  float rd = rsqrtf((float)(deg < 1 ? 1 : deg));
  uint4 o;
  o.x = pack_bf2(a0 * rd, a1 * rd);
  o.y = pack_bf2(a2 * rd, a3 * rd);
  o.z = pack_bf2(a4 * rd, a5 * rd);
  o.w = pack_bf2(a6 * rd, a7 * rd);
  *(uint4*)orow = o;
}

// ------------------------- transpose + cast weights to bf16 (tiny, once)
__global__ void wprep(const float* __restrict__ W0, const float* __restrict__ W1,
                      const float* __restrict__ W2, const float* __restrict__ L0,
                      const float* __restrict__ L1, const float* __restrict__ L2,
                      unsigned short* __restrict__ Wt, unsigned short* __restrict__ Wt2) {
  int i = blockIdx.x * 256 + threadIdx.x;
  if (i < 3 * 16384) {
    int t = i / 16384, r = i % 16384, n = r / 128, k = r % 128;
    const float* W = (t == 0) ? W0 : ((t == 1) ? W1 : W2);
    Wt[i] = f2bf(W[k * 128 + n]);           // Wt[t][n][k] = W[k][n]
  } else if (i < 3 * 16384 + 3 * 8192) {
    int j = i - 3 * 16384;
    int t = j / 8192, r = j % 8192, n = r / 128, k = r % 128;
    const float* L = (t == 0) ? L0 : ((t == 1) ? L1 : L2);
    Wt2[j] = f2bf(L[k * 64 + n]);           // Wt2[t][n][k] = Wl[k][n]
  }
}

// ---- fused MFMA GEMM, persistent blocks: O = (leaky(A@W+b))@Wl + bl
__global__ __launch_bounds__(256) void gemm_fused(
    const unsigned short* __restrict__ aggb,
    const unsigned short* __restrict__ Wt,   // 3 x [128 x 128] (n-major)
    const unsigned short* __restrict__ Wt2,  // 3 x [64 x 128]  (n-major)
    const float* __restrict__ b0, const float* __restrict__ b1, const float* __restrict__ b2,
    const float* __restrict__ l0, const float* __restrict__ l1, const float* __restrict__ l2,
    float* __restrict__ out) {
  __shared__ __align__(16) unsigned short sW1[128 * 136];   // 34816 B
  __shared__ __align__(16) unsigned short sH[4][16 * 136];  // 17408 B (per-wave)
  const int bid = blockIdx.x;
  int t, bl, nb, ntile, padbase, outbase, mcnt;
  if (bid < 226)      { t = 0; bl = bid;       nb = 226; ntile = 782;  padbase = P_SVC_BASE;  outbase = 0;     mcnt = 50000; }
  else if (bid < 316) { t = 1; bl = bid - 226; nb = 90;  ntile = 313;  padbase = P_NODE_BASE; outbase = 50000; mcnt = 20000; }
  else                { t = 2; bl = bid - 316; nb = 452; ntile = 1563; padbase = P_POD_BASE;  outbase = 70000; mcnt = 100000; }
  const float* bp = (t == 0) ? b0 : ((t == 1) ? b1 : b2);
  const float* lp = (t == 0) ? l0 : ((t == 1) ? l1 : l2);

  // stage W1 into LDS (2048 x 16B units)
  const unsigned short* W1g = Wt + t * 16384;
  for (int uu = threadIdx.x; uu < 2048; uu += 256) {
    short8 v = *(const short8*)(W1g + uu * 8);
    *(short8*)(&sW1[(uu >> 4) * 136 + (uu & 15) * 8]) = v;
  }
  const int wv = threadIdx.x >> 6, lane = threadIdx.x & 63;
  const int quad = lane >> 4, l16 = lane & 15;

  // W2 fragments + biases in registers (per lane)
  const unsigned short* W2g = Wt2 + t * 8192;
  short8 w2f[4][4];
  #pragma unroll
  for (int n = 0; n < 4; n++)
    #pragma unroll
    for (int kt = 0; kt < 4; kt++)
      w2f[n][kt] = *(const short8*)(W2g + (n * 16 + l16) * 128 + kt * 32 + quad * 8);
  float bias1[8], bias2[4];
  #pragma unroll
  for (int n = 0; n < 8; n++) bias1[n] = bp[n * 16 + l16];
  #pragma unroll
  for (int n = 0; n < 4; n++) bias2[n] = lp[n * 16 + l16];
  __syncthreads();

  for (int tile = bl; tile < ntile; tile += nb) {
    const unsigned short* Arow = aggb + (size_t)(padbase + tile * 64 + wv * 16 + l16) * 128;
    floatx4 acc[8];
    #pragma unroll
    for (int n = 0; n < 8; n++) acc[n] = (floatx4){0.f, 0.f, 0.f, 0.f};
    #pragma unroll
    for (int kt = 0; kt < 4; kt++) {
      short8 af = *(const short8*)(Arow + kt * 32 + quad * 8);
      #pragma unroll
      for (int n = 0; n < 8; n++) {
        short8 bf = *(const short8*)(&sW1[(n * 16 + l16) * 136 + kt * 32 + quad * 8]);
        acc[n] = __builtin_amdgcn_mfma_f32_16x16x32_bf16(af, bf, acc[n], 0, 0, 0);
      }
    }
    // bias + leaky, C-layout -> per-wave LDS tile (row-major, stride 136)
    #pragma unroll
    for (int n = 0; n < 8; n++) {
      #pragma unroll
      for (int i = 0; i < 4; i++) {
        float h = acc[n][i] + bias1[n];
        h = (h > 0.f) ? h : 0.01f * h;
        sH[wv][(quad * 4 + i) * 136 + n * 16 + l16] = f2bf(h);
      }
    }
    // GEMM2 from per-wave LDS (intra-wave dep; compiler orders via lgkmcnt)
    floatx4 acc2[4];
    #pragma unroll
    for (int n = 0; n < 4; n++) acc2[n] = (floatx4){0.f, 0.f, 0.f, 0.f};
    #pragma unroll
    for (int kt = 0; kt < 4; kt++) {
      short8 af = *(const short8*)(&sH[wv][l16 * 136 + kt * 32 + quad * 8]);
      #pragma unroll
      for (int n = 0; n < 4; n++)
        acc2[n] = __builtin_amdgcn_mfma_f32_16x16x32_bf16(af, w2f[n][kt], acc2[n], 0, 0, 0);
    }
    int r0 = tile * 64 + wv * 16 + quad * 4;   // type-local row
    #pragma unroll
    for (int n = 0; n < 4; n++) {
      #pragma unroll
      for (int i = 0; i < 4; i++) {
        int r = r0 + i;
        if (r < mcnt) out[(size_t)(outbase + r) * 64 + n * 16 + l16] = acc2[n][i] + bias2[n];
      }
    }
  }
}

extern "C" void kernel_launch(void* const* d_in, const int* in_sizes, int n_in,
                              void* d_out, int out_size, void* d_ws, size_t ws_size,
                              hipStream_t stream) {
  const float* x_svc  = (const float*)d_in[0];
  const float* x_pod  = (const float*)d_in[1];
  const float* x_node = (const float*)d_in[2];
  const int* svc_src  = (const int*)d_in[3];
  const int* svc_dst  = (const int*)d_in[4];
  const int* pn_src   = (const int*)d_in[5];
  const int* pn_dst   = (const int*)d_in[6];
  const int* np_src   = (const int*)d_in[7];
  const int* np_dst   = (const int*)d_in[8];
  const float* W_call = (const float*)d_in[9];
  const float* b_call = (const float*)d_in[10];
  const float* W_in   = (const float*)d_in[11];
  const float* b_in   = (const float*)d_in[12];
  const float* W_ni   = (const float*)d_in[13];
  const float* b_ni   = (const float*)d_in[14];
  const float* W_ls   = (const float*)d_in[15];
  const float* b_ls   = (const float*)d_in[16];
  const float* W_ln   = (const float*)d_in[17];
  const float* b_ln   = (const float*)d_in[18];
  const float* W_lp   = (const float*)d_in[19];
  const float* b_lp   = (const float*)d_in[20];
  float* out = (float*)d_out;

  // workspace layout (lifetimes):
  //   dcur     @ 0        (5316 B)
  //   scur     @ 5504     (5316 B)
  //   rowrange @ 11008    (170000 int2 -> ends 1371008)
  //   cnt_src  @ 1371008  (170000 int  -> ends 2051008)
  //   csr      @ 2051072  (DST_CAP_TOT ints -> ends 14220288)
  //   Wt       @ 14220288 (98304 B)
  //   Wt2      @ 14318592 (49152 B)
  //   Xn       @ 14367744 (43.52 MB -> ends 57887744)
  //   dstbuf   @ 14367744 (12.17 MB, aliases Xn: dead before normalize writes Xn)
  //   srcbuf   @ 26537088 (3.04 MB, aliases Xn tail: dead before normalize)
  //   aggb     @ 57887744 (43.55 MB -> ends 101436416)
  char* ws = (char*)d_ws;
  int*  dcur     = (int*)(ws + 0);
  int*  scur     = (int*)(ws + 5504);
  int2* rowrange = (int2*)(ws + 11008);
  int*  cnt_src  = (int*)(ws + 1371008);
  int*  csr      = (int*)(ws + 2051072);
  unsigned short* Wt  = (unsigned short*)(ws + 14220288);
  unsigned short* Wt2 = (unsigned short*)(ws + 14318592);
  unsigned* Xn     = (unsigned*)(ws + 14367744);
  unsigned* dstbuf = (unsigned*)(ws + 14367744);
  unsigned char* srcbuf = (unsigned char*)(ws + 26537088);
  unsigned* aggb   = (unsigned*)(ws + 57887744);

  init_cur<<<2, 1024, 0, stream>>>(dcur, scur);
  scatter_onepass<<<NBLK, 1024, 0, stream>>>(svc_src, svc_dst, pn_src, pn_dst,
                                             np_src, np_dst, dcur, scur, dstbuf, srcbuf);
  finalize_all<<<2 * NBUCK, 256, 0, stream>>>(dcur, scur, dstbuf, srcbuf,
                                              rowrange, csr, cnt_src);
  wprep<<<288, 256, 0, stream>>>(W_call, W_in, W_ni, W_ls, W_ln, W_lp, Wt, Wt2);
  normalize_cast<<<21250, 256, 0, stream>>>(x_svc, x_pod, x_node, cnt_src, Xn);
  aggregate_svc<<<SVC_BLOCKS, 256, 0, stream>>>(Xn, rowrange, csr, aggb);
  aggregate_np<<<NP_BLOCKS, 256, 0, stream>>>(Xn, rowrange, csr, aggb);
  gemm_fused<<<768, 256, 0, stream>>>((const unsigned short*)aggb, Wt, Wt2,
                                      b_call, b_in, b_ni, b_ls, b_ln, b_lp, out);
}

// Round 7
// 303.830 us; speedup vs baseline: 1.0668x; 1.0327x over previous
//
#include <hip/hip_runtime.h>

typedef __attribute__((ext_vector_type(8))) short short8;
typedef __attribute__((ext_vector_type(4))) float floatx4;

#define N_SVC  50000
#define N_NODE 20000
#define N_POD  100000
#define E_SVC  1600000
#define E_PN   100000
#define E_NP   100000
#define N_TOT  170000   // dst order: svc [0,50k), node [50k,70k), pod [70k,170k)
#define E_TOT  1800000
#define NBUCK  1329     // ceil(170000/128), bucket = unified_id >> 7
#define NBLK   256
#define PER_BLK 7032    // ceil(E_TOT/NBLK)
// padded dst layout for MFMA tiles (each type padded to x64 rows):
#define P_SVC_BASE  0
#define P_NODE_BASE 50048
#define P_POD_BASE  70080
#define P_TOT       170112
// aggregate split: svc = wave-per-row (50048 waves); node/pod = 4 rows/wave
#define SVC_WAVES   50048
#define SVC_BLOCKS  12512   // SVC_WAVES/4
#define NP_WAVES    30016   // (P_TOT - SVC_WAVES)/4
#define NP_BLOCKS   7504    // NP_WAVES/4
// src unified order (cnt_src): svc [0,50k), pod [50k,150k), node [150k,170k)
// Xn (bf16 normalized) holds ONLY svc srcs [0,50k) -- pod/node srcs are
// gathered directly from the f32 inputs in aggregate_np (reuse ~1x / ~5x,
// so the bf16 staging round-trip was pure waste; also shrinks the svc
// gather table to 12.8 MB for better L2/L3 residency).

__device__ __forceinline__ unsigned short f2bf(float f) {
  union { float f; unsigned u; } v; v.f = f;
  unsigned r = v.u + 0x7FFFu + ((v.u >> 16) & 1u);   // RNE
  return (unsigned short)(r >> 16);
}
__device__ __forceinline__ unsigned pack_bf2(float a, float b) {
  return (unsigned)f2bf(a) | ((unsigned)f2bf(b) << 16);
}
__device__ __forceinline__ float bfl(unsigned u) { union { unsigned u; float f; } v; v.u = u << 16; return v.f; }
__device__ __forceinline__ float bfh(unsigned u) { union { unsigned u; float f; } v; v.u = u & 0xFFFF0000u; return v.f; }

// static bucket capacity layout (over-provisioned >= mean + 30 sigma)
// NOTE (measured r5): coarser 1024-row buckets REGRESSED (~+16 us): 167-counter
// LDS hist has 8x atomic contention, and 334-block finalize is imbalance-bound.
// 128-row buckets are the measured sweet spot.
// dst buckets: svc [0,391] cap 6144 | node (391,547] cap 1536 | pod (547,1328] cap 512
__device__ __forceinline__ int dbase_of(int b) {
  if (b <= 391) return b * 6144;
  if (b <= 547) return 2402304 + (b - 391) * 1536;
  return 2641920 + (b - 547) * 512;
}
#define DST_CAP_TOT 3042304
// src buckets: svc [0,391] cap 6144 | pod (391,1171] cap 512 | node (1171,1328] cap 1536
__device__ __forceinline__ int sbase_of(int b) {
  if (b <= 391) return b * 6144;
  if (b <= 1171) return 2402304 + (b - 391) * 512;
  return 2801664 + (b - 1171) * 1536;
}
#define SRC_CAP_TOT 3044352

// unified-id edge loader: src order svc/pod/node, dst order svc/node/pod
__device__ __forceinline__ void load_edge(int i,
    const int* __restrict__ svcS, const int* __restrict__ svcD,
    const int* __restrict__ pnS, const int* __restrict__ pnD,
    const int* __restrict__ npS, const int* __restrict__ npD,
    int& S, int& D) {
  if (i < E_SVC)             { S = svcS[i];                         D = svcD[i]; }
  else if (i < E_SVC + E_PN) { int j = i - E_SVC;        S = pnS[j] + 50000;  D = pnD[j] + 50000; }
  else                       { int j = i - E_SVC - E_PN; S = npS[j] + 150000; D = npD[j] + 70000; }
}

// ---------------- weight prep + cursor init (fused; launched first)
__global__ void wprep_init(const float* __restrict__ W0, const float* __restrict__ W1,
                           const float* __restrict__ W2, const float* __restrict__ L0,
                           const float* __restrict__ L1, const float* __restrict__ L2,
                           unsigned short* __restrict__ Wt, unsigned short* __restrict__ Wt2,
                           int* __restrict__ dcur, int* __restrict__ scur) {
  int i = blockIdx.x * 256 + threadIdx.x;
  if (i < NBUCK) { dcur[i] = dbase_of(i); scur[i] = sbase_of(i); }
  if (i < 3 * 16384) {
    int t = i / 16384, r = i % 16384, n = r / 128, k = r % 128;
    const float* W = (t == 0) ? W0 : ((t == 1) ? W1 : W2);
    Wt[i] = f2bf(W[k * 128 + n]);           // Wt[t][n][k] = W[k][n]
  } else if (i < 3 * 16384 + 3 * 8192) {
    int j = i - 3 * 16384;
    int t = j / 8192, r = j % 8192, n = r / 128, k = r % 128;
    const float* L = (t == 0) ? L0 : ((t == 1) ? L1 : L2);
    Wt2[j] = f2bf(L[k * 64 + n]);           // Wt2[t][n][k] = Wl[k][n]
  }
}

// ---------------- single-pass partition: edges in regs, LDS hist, reserve, scatter
// NOTE (measured r1): direct global atomicAdd for src degrees is memory-side on
// MI355X (65 MB write-back, 90 us) -- all per-edge atomics stay in LDS.
__global__ __launch_bounds__(1024) void scatter_onepass(
    const int* __restrict__ svcS, const int* __restrict__ svcD,
    const int* __restrict__ pnS, const int* __restrict__ pnD,
    const int* __restrict__ npS, const int* __restrict__ npD,
    int* __restrict__ dcur, int* __restrict__ scur,
    unsigned* __restrict__ dstbuf, unsigned char* __restrict__ srcbuf) {
  __shared__ int ldc[NBUCK], lsc[NBUCK];
  const int tid = threadIdx.x;
  for (int t = tid; t < NBUCK; t += 1024) { ldc[t] = 0; lsc[t] = 0; }
  __syncthreads();
  const int lo = blockIdx.x * PER_BLK;
  const int hi = (lo + PER_BLK < E_TOT) ? lo + PER_BLK : E_TOT;
  int Sv[7], Dv[7];
  #pragma unroll
  for (int k = 0; k < 7; ++k) {
    int e = lo + tid + k * 1024;
    if (e < hi) {
      load_edge(e, svcS, svcD, pnS, pnD, npS, npD, Sv[k], Dv[k]);
      atomicAdd(&ldc[Dv[k] >> 7], 1);
      atomicAdd(&lsc[Sv[k] >> 7], 1);
    } else Sv[k] = -1;
  }
  __syncthreads();
  for (int t = tid; t < NBUCK; t += 1024) {
    int c = ldc[t];  ldc[t] = c ? atomicAdd(&dcur[t], c) : 0;
    int c2 = lsc[t]; lsc[t] = c2 ? atomicAdd(&scur[t], c2) : 0;
  }
  __syncthreads();
  #pragma unroll
  for (int k = 0; k < 7; ++k) {
    if (Sv[k] >= 0) {
      int p = atomicAdd(&ldc[Dv[k] >> 7], 1);
      dstbuf[p] = ((unsigned)(Dv[k] & 127) << 18) | (unsigned)Sv[k];
      int q = atomicAdd(&lsc[Sv[k] >> 7], 1);
      srcbuf[q] = (unsigned char)(Sv[k] & 127);
    }
  }
}

// ---------------- finalize: dst CSR + rowrange (blocks [0,NBUCK)), src counts (rest)
__global__ __launch_bounds__(256) void finalize_all(
    const int* __restrict__ dcur, const int* __restrict__ scur,
    const unsigned* __restrict__ dstbuf, const unsigned char* __restrict__ srcbuf,
    int2* __restrict__ rowrange, int* __restrict__ csr, int* __restrict__ cnt_src) {
  __shared__ int lcnt[128], lcur[128];
  __shared__ int s_w0;
  const int tid = threadIdx.x;
  if (blockIdx.x < NBUCK) {
    const int b = blockIdx.x;
    const int base = dbase_of(b);
    const int cnt = dcur[b] - base;
    if (tid < 128) lcnt[tid] = 0;
    __syncthreads();
    for (int e = tid; e < cnt; e += 256) atomicAdd(&lcnt[dstbuf[base + e] >> 18], 1);
    __syncthreads();
    int excl = 0, v = 0;
    if (tid < 128) {
      v = lcnt[tid];
      int lane = tid & 63;
      int x = v;
      #pragma unroll
      for (int off = 1; off < 64; off <<= 1) {
        int y = __shfl_up(x, off, 64);
        if (lane >= off) x += y;
      }
      excl = x - v;
      if (tid == 63) s_w0 = x;
    }
    __syncthreads();
    if (tid < 128) {
      if (tid >= 64) excl += s_w0;
      lcur[tid] = excl;
      int u = b * 128 + tid;
      if (u < N_TOT) rowrange[u] = make_int2(base + excl, base + excl + v);
    }
    __syncthreads();
    for (int e = tid; e < cnt; e += 256) {
      unsigned wv = dstbuf[base + e];
      int p = atomicAdd(&lcur[wv >> 18], 1);
      csr[base + p] = (int)(wv & 0x3FFFFu);
    }
  } else {
    const int b = blockIdx.x - NBUCK;
    const int base = sbase_of(b);
    const int cnt = scur[b] - base;
    if (tid < 128) lcnt[tid] = 0;
    __syncthreads();
    for (int e = tid; e < cnt; e += 256) atomicAdd(&lcnt[srcbuf[base + e]], 1);
    __syncthreads();
    if (tid < 128) {
      int u = b * 128 + tid;
      if (u < N_TOT) cnt_src[u] = lcnt[tid];
    }
  }
}

// --------------------------- normalize svc srcs by rsqrt(deg) -> bf16 table
// svc rows only (50k x 128); pod/node srcs are read f32-direct in aggregate_np.
__global__ void normalize_cast(const float* __restrict__ xs, const int* __restrict__ cs,
                               unsigned* __restrict__ Xn) {
  int i = blockIdx.x * blockDim.x + threadIdx.x;   // quad id
  if (i >= N_SVC * 32) return;
  int row = i >> 5, c4 = i & 31;
  const float* src = xs + (size_t)row * 128;
  int cc = cs[row]; if (cc < 1) cc = 1;
  float r = rsqrtf((float)cc);
  float4 v = ((const float4*)src)[c4];
  uint2 o;
  o.x = pack_bf2(v.x * r, v.y * r);
  o.y = pack_bf2(v.z * r, v.w * r);
  *(uint2*)(Xn + (size_t)row * 64 + c4 * 2) = o;
}

#define ACC8(v) { a0 += bfl(v.x); a1 += bfh(v.x); a2 += bfl(v.y); a3 += bfh(v.y); \
                  a4 += bfl(v.z); a5 += bfh(v.z); a6 += bfl(v.w); a7 += bfh(v.w); }

// ------------------ aggregation, svc rows: wave-per-row, 4 edge-slots x 16
// lanes, 32-edge unroll -> 8 gathers in flight (r3/r4: BW scales with
// in-flight gathers at constant FETCH_SIZE). Xn is now 12.8 MB (svc-only).
__global__ __launch_bounds__(256) void aggregate_svc(
    const unsigned* __restrict__ Xn, const int2* __restrict__ rowrange,
    const int* __restrict__ csr, unsigned* __restrict__ aggb) {
  const int lane = threadIdx.x & 63;
  const int gw = blockIdx.x * 4 + (threadIdx.x >> 6);
  const int grp = lane >> 4, l16 = lane & 15;
  const unsigned* Xb = Xn + l16 * 4;
  unsigned* orow = aggb + (size_t)gw * 64 + l16 * 4;
  if (gw >= 50000) {
    if (gw < SVC_WAVES && grp == 0) *(uint4*)orow = (uint4){0u, 0u, 0u, 0u};
    return;
  }
  int2 rr = rowrange[gw];
  int beg = rr.x, end = rr.y;
  int deg = end - beg;
  float a0 = 0.f, a1 = 0.f, a2 = 0.f, a3 = 0.f, a4 = 0.f, a5 = 0.f, a6 = 0.f, a7 = 0.f;
  int e = beg;
  for (; e + 32 <= end; e += 32) {
    int s0 = csr[e + grp];
    int s1 = csr[e + 4 + grp];
    int s2 = csr[e + 8 + grp];
    int s3 = csr[e + 12 + grp];
    int s4 = csr[e + 16 + grp];
    int s5 = csr[e + 20 + grp];
    int s6 = csr[e + 24 + grp];
    int s7 = csr[e + 28 + grp];
    uint4 v0 = *(const uint4*)(Xb + (unsigned)s0 * 64);
    uint4 v1 = *(const uint4*)(Xb + (unsigned)s1 * 64);
    uint4 v2 = *(const uint4*)(Xb + (unsigned)s2 * 64);
    uint4 v3 = *(const uint4*)(Xb + (unsigned)s3 * 64);
    uint4 v4 = *(const uint4*)(Xb + (unsigned)s4 * 64);
    uint4 v5 = *(const uint4*)(Xb + (unsigned)s5 * 64);
    uint4 v6 = *(const uint4*)(Xb + (unsigned)s6 * 64);
    uint4 v7 = *(const uint4*)(Xb + (unsigned)s7 * 64);
    ACC8(v0) ACC8(v1) ACC8(v2) ACC8(v3) ACC8(v4) ACC8(v5) ACC8(v6) ACC8(v7)
  }
  for (; e + 16 <= end; e += 16) {
    int s0 = csr[e + grp];
    int s1 = csr[e + 4 + grp];
    int s2 = csr[e + 8 + grp];
    int s3 = csr[e + 12 + grp];
    uint4 v0 = *(const uint4*)(Xb + (unsigned)s0 * 64);
    uint4 v1 = *(const uint4*)(Xb + (unsigned)s1 * 64);
    uint4 v2 = *(const uint4*)(Xb + (unsigned)s2 * 64);
    uint4 v3 = *(const uint4*)(Xb + (unsigned)s3 * 64);
    ACC8(v0) ACC8(v1) ACC8(v2) ACC8(v3)
  }
  for (; e + 8 <= end; e += 8) {
    int s0 = csr[e + grp];
    int s1 = csr[e + 4 + grp];
    uint4 v0 = *(const uint4*)(Xb + (unsigned)s0 * 64);
    uint4 v1 = *(const uint4*)(Xb + (unsigned)s1 * 64);
    ACC8(v0) ACC8(v1)
  }
  for (; e + 4 <= end; e += 4) {
    int s = csr[e + grp];
    uint4 v = *(const uint4*)(Xb + (unsigned)s * 64);
    ACC8(v)
  }
  if (grp < end - e) {
    int s = csr[e + grp];
    uint4 v = *(const uint4*)(Xb + (unsigned)s * 64);
    ACC8(v)
  }
  // reduce across the 4 edge-slots (lanes l, l+16, l+32, l+48)
  a0 += __shfl_xor(a0, 32, 64); a1 += __shfl_xor(a1, 32, 64);
  a2 += __shfl_xor(a2, 32, 64); a3 += __shfl_xor(a3, 32, 64);
  a4 += __shfl_xor(a4, 32, 64); a5 += __shfl_xor(a5, 32, 64);
  a6 += __shfl_xor(a6, 32, 64); a7 += __shfl_xor(a7, 32, 64);
  a0 += __shfl_xor(a0, 16, 64); a1 += __shfl_xor(a1, 16, 64);
  a2 += __shfl_xor(a2, 16, 64); a3 += __shfl_xor(a3, 16, 64);
  a4 += __shfl_xor(a4, 16, 64); a5 += __shfl_xor(a5, 16, 64);
  a6 += __shfl_xor(a6, 16, 64); a7 += __shfl_xor(a7, 16, 64);
  float rd = rsqrtf((float)(deg < 1 ? 1 : deg));
  if (grp == 0) {
    uint4 o;
    o.x = pack_bf2(a0 * rd, a1 * rd);
    o.y = pack_bf2(a2 * rd, a3 * rd);
    o.z = pack_bf2(a4 * rd, a5 * rd);
    o.w = pack_bf2(a6 * rd, a7 * rd);
    *(uint4*)orow = o;
  }
}

// ------------------ aggregation, node/pod rows (mean deg 5 / 1):
// one 16-lane group per row, 4 rows per wave. Gathers f32 source rows
// DIRECTLY from x_pod / x_node with in-loop rsqrt(deg_src) normalization
// (no bf16 staging round-trip; srcs reused ~1x / ~5x, L2/L3-resident).
__global__ __launch_bounds__(256) void aggregate_np(
    const float* __restrict__ xp, const float* __restrict__ xn,
    const int* __restrict__ cnt_src, const int2* __restrict__ rowrange,
    const int* __restrict__ csr, unsigned* __restrict__ aggb) {
  const int lane = threadIdx.x & 63;
  const int w = blockIdx.x * 4 + (threadIdx.x >> 6);
  const int grp = lane >> 4, l16 = lane & 15;
  const int row = SVC_WAVES + w * 4 + grp;   // padded row id
  if (row >= P_TOT) return;
  int u; bool valid; const float* Xf; int soff;
  if (row < P_POD_BASE) { u = row - 48; valid = (row - P_NODE_BASE) < 20000; Xf = xp; soff = 50000; }
  else                  { u = row - 80; valid = (row - P_POD_BASE) < 100000; Xf = xn; soff = 150000; }
  unsigned* orow = aggb + (size_t)row * 64 + l16 * 4;
  if (!valid) {
    *(uint4*)orow = (uint4){0u, 0u, 0u, 0u};
    return;
  }
  const float* Xb = Xf + l16 * 8;
  int2 rr = rowrange[u];
  int beg = rr.x, end = rr.y;
  int deg = end - beg;
  float a0 = 0.f, a1 = 0.f, a2 = 0.f, a3 = 0.f, a4 = 0.f, a5 = 0.f, a6 = 0.f, a7 = 0.f;
  int e = beg;
  for (; e + 2 <= end; e += 2) {
    int s0 = csr[e], s1 = csr[e + 1];
    int c0 = cnt_src[s0]; if (c0 < 1) c0 = 1;
    int c1 = cnt_src[s1]; if (c1 < 1) c1 = 1;
    float r0 = rsqrtf((float)c0), r1 = rsqrtf((float)c1);
    const float* p0 = Xb + (size_t)(s0 - soff) * 128;
    const float* p1 = Xb + (size_t)(s1 - soff) * 128;
    float4 u0 = *(const float4*)p0;
    float4 u1 = *(const float4*)(p0 + 4);
    float4 w0 = *(const float4*)p1;
    float4 w1 = *(const float4*)(p1 + 4);
    a0 += u0.x * r0 + w0.x * r1; a1 += u0.y * r0 + w0.y * r1;
    a2 += u0.z * r0 + w0.z * r1; a3 += u0.w * r0 + w0.w * r1;
    a4 += u1.x * r0 + w1.x * r1; a5 += u1.y * r0 + w1.y * r1;
    a6 += u1.z * r0 + w1.z * r1; a7 += u1.w * r0 + w1.w * r1;
  }
  if (e < end) {
    int s = csr[e];
    int c = cnt_src[s]; if (c < 1) c = 1;
    float r = rsqrtf((float)c);
    const float* p = Xb + (size_t)(s - soff) * 128;
    float4 u0 = *(const float4*)p;
    float4 u1 = *(const float4*)(p + 4);
    a0 += u0.x * r; a1 += u0.y * r; a2 += u0.z * r; a3 += u0.w * r;
    a4 += u1.x * r; a5 += u1.y * r; a6 += u1.z * r; a7 += u1.w * r;
  }
  float rd = rsqrtf((float)(deg < 1 ? 1 : deg));
  uint4 o;
  o.x = pack_bf2(a0 * rd, a1 * rd);
  o.y = pack_bf2(a2 * rd, a3 * rd);
  o.z = pack_bf2(a4 * rd, a5 * rd);
  o.w = pack_bf2(a6 * rd, a7 * rd);
  *(uint4*)orow = o;
}

// ---- fused MFMA GEMM, persistent blocks: O = (leaky(A@W+b))@Wl + bl
__global__ __launch_bounds__(256) void gemm_fused(
    const unsigned short* __restrict__ aggb,
    const unsigned short* __restrict__ Wt,   // 3 x [128 x 128] (n-major)
    const unsigned short* __restrict__ Wt2,  // 3 x [64 x 128]  (n-major)
    const float* __restrict__ b0, const float* __restrict__ b1, const float* __restrict__ b2,
    const float* __restrict__ l0, const float* __restrict__ l1, const float* __restrict__ l2,
    float* __restrict__ out) {
  __shared__ __align__(16) unsigned short sW1[128 * 136];   // 34816 B
  __shared__ __align__(16) unsigned short sH[4][16 * 136];  // 17408 B (per-wave)
  const int bid = blockIdx.x;
  int t, bl, nb, ntile, padbase, outbase, mcnt;
  if (bid < 226)      { t = 0; bl = bid;       nb = 226; ntile = 782;  padbase = P_SVC_BASE;  outbase = 0;     mcnt = 50000; }
  else if (bid < 316) { t = 1; bl = bid - 226; nb = 90;  ntile = 313;  padbase = P_NODE_BASE; outbase = 50000; mcnt = 20000; }
  else                { t = 2; bl = bid - 316; nb = 452; ntile = 1563; padbase = P_POD_BASE;  outbase = 70000; mcnt = 100000; }
  const float* bp = (t == 0) ? b0 : ((t == 1) ? b1 : b2);
  const float* lp = (t == 0) ? l0 : ((t == 1) ? l1 : l2);

  // stage W1 into LDS (2048 x 16B units)
  const unsigned short* W1g = Wt + t * 16384;
  for (int uu = threadIdx.x; uu < 2048; uu += 256) {
    short8 v = *(const short8*)(W1g + uu * 8);
    *(short8*)(&sW1[(uu >> 4) * 136 + (uu & 15) * 8]) = v;
  }
  const int wv = threadIdx.x >> 6, lane = threadIdx.x & 63;
  const int quad = lane >> 4, l16 = lane & 15;

  // W2 fragments + biases in registers (per lane)
  const unsigned short* W2g = Wt2 + t * 8192;
  short8 w2f[4][4];
  #pragma unroll
  for (int n = 0; n < 4; n++)
    #pragma unroll
    for (int kt = 0; kt < 4; kt++)
      w2f[n][kt] = *(const short8*)(W2g + (n * 16 + l16) * 128 + kt * 32 + quad * 8);
  float bias1[8], bias2[4];
  #pragma unroll
  for (int n = 0; n < 8; n++) bias1[n] = bp[n * 16 + l16];
  #pragma unroll
  for (int n = 0; n < 4; n++) bias2[n] = lp[n * 16 + l16];
  __syncthreads();

  for (int tile = bl; tile < ntile; tile += nb) {
    const unsigned short* Arow = aggb + (size_t)(padbase + tile * 64 + wv * 16 + l16) * 128;
    floatx4 acc[8];
    #pragma unroll
    for (int n = 0; n < 8; n++) acc[n] = (floatx4){0.f, 0.f, 0.f, 0.f};
    #pragma unroll
    for (int kt = 0; kt < 4; kt++) {
      short8 af = *(const short8*)(Arow + kt * 32 + quad * 8);
      #pragma unroll
      for (int n = 0; n < 8; n++) {
        short8 bf = *(const short8*)(&sW1[(n * 16 + l16) * 136 + kt * 32 + quad * 8]);
        acc[n] = __builtin_amdgcn_mfma_f32_16x16x32_bf16(af, bf, acc[n], 0, 0, 0);
      }
    }
    // bias + leaky, C-layout -> per-wave LDS tile (row-major, stride 136)
    #pragma unroll
    for (int n = 0; n < 8; n++) {
      #pragma unroll
      for (int i = 0; i < 4; i++) {
        float h = acc[n][i] + bias1[n];
        h = (h > 0.f) ? h : 0.01f * h;
        sH[wv][(quad * 4 + i) * 136 + n * 16 + l16] = f2bf(h);
      }
    }
    // GEMM2 from per-wave LDS (intra-wave dep; compiler orders via lgkmcnt)
    floatx4 acc2[4];
    #pragma unroll
    for (int n = 0; n < 4; n++) acc2[n] = (floatx4){0.f, 0.f, 0.f, 0.f};
    #pragma unroll
    for (int kt = 0; kt < 4; kt++) {
      short8 af = *(const short8*)(&sH[wv][l16 * 136 + kt * 32 + quad * 8]);
      #pragma unroll
      for (int n = 0; n < 4; n++)
        acc2[n] = __builtin_amdgcn_mfma_f32_16x16x32_bf16(af, w2f[n][kt], acc2[n], 0, 0, 0);
    }
    int r0 = tile * 64 + wv * 16 + quad * 4;   // type-local row
    #pragma unroll
    for (int n = 0; n < 4; n++) {
      #pragma unroll
      for (int i = 0; i < 4; i++) {
        int r = r0 + i;
        if (r < mcnt) out[(size_t)(outbase + r) * 64 + n * 16 + l16] = acc2[n][i] + bias2[n];
      }
    }
  }
}

extern "C" void kernel_launch(void* const* d_in, const int* in_sizes, int n_in,
                              void* d_out, int out_size, void* d_ws, size_t ws_size,
                              hipStream_t stream) {
  const float* x_svc  = (const float*)d_in[0];
  const float* x_pod  = (const float*)d_in[1];
  const float* x_node = (const float*)d_in[2];
  const int* svc_src  = (const int*)d_in[3];
  const int* svc_dst  = (const int*)d_in[4];
  const int* pn_src   = (const int*)d_in[5];
  const int* pn_dst   = (const int*)d_in[6];
  const int* np_src   = (const int*)d_in[7];
  const int* np_dst   = (const int*)d_in[8];
  const float* W_call = (const float*)d_in[9];
  const float* b_call = (const float*)d_in[10];
  const float* W_in   = (const float*)d_in[11];
  const float* b_in   = (const float*)d_in[12];
  const float* W_ni   = (const float*)d_in[13];
  const float* b_ni   = (const float*)d_in[14];
  const float* W_ls   = (const float*)d_in[15];
  const float* b_ls   = (const float*)d_in[16];
  const float* W_ln   = (const float*)d_in[17];
  const float* b_ln   = (const float*)d_in[18];
  const float* W_lp   = (const float*)d_in[19];
  const float* b_lp   = (const float*)d_in[20];
  float* out = (float*)d_out;

  // workspace layout (lifetimes):
  //   dcur     @ 0        (5316 B)
  //   scur     @ 5504     (5316 B)
  //   rowrange @ 11008    (170000 int2 -> ends 1371008)
  //   cnt_src  @ 1371008  (170000 int  -> ends 2051008)
  //   csr      @ 2051072  (DST_CAP_TOT ints -> ends 14220288)
  //   Wt       @ 14220288 (98304 B)
  //   Wt2      @ 14318592 (49152 B)
  //   Xn       @ 14367744 (svc-only bf16: 50048*256 B = 12.81 MB -> ends 27180032)
  //   dstbuf   @ 14367744 (12.17 MB, aliases Xn: dead before normalize writes Xn)
  //   srcbuf   @ 27180032 (3.04 MB -> ends 30224384)
  //   aggb     @ 30224384 (43.55 MB -> ends 73773056)
  char* ws = (char*)d_ws;
  int*  dcur     = (int*)(ws + 0);
  int*  scur     = (int*)(ws + 5504);
  int2* rowrange = (int2*)(ws + 11008);
  int*  cnt_src  = (int*)(ws + 1371008);
  int*  csr      = (int*)(ws + 2051072);
  unsigned short* Wt  = (unsigned short*)(ws + 14220288);
  unsigned short* Wt2 = (unsigned short*)(ws + 14318592);
  unsigned* Xn     = (unsigned*)(ws + 14367744);
  unsigned* dstbuf = (unsigned*)(ws + 14367744);
  unsigned char* srcbuf = (unsigned char*)(ws + 27180032);
  unsigned* aggb   = (unsigned*)(ws + 30224384);

  wprep_init<<<288, 256, 0, stream>>>(W_call, W_in, W_ni, W_ls, W_ln, W_lp,
                                      Wt, Wt2, dcur, scur);
  scatter_onepass<<<NBLK, 1024, 0, stream>>>(svc_src, svc_dst, pn_src, pn_dst,
                                             np_src, np_dst, dcur, scur, dstbuf, srcbuf);
  finalize_all<<<2 * NBUCK, 256, 0, stream>>>(dcur, scur, dstbuf, srcbuf,
                                              rowrange, csr, cnt_src);
  normalize_cast<<<6250, 256, 0, stream>>>(x_svc, cnt_src, Xn);
  aggregate_svc<<<SVC_BLOCKS, 256, 0, stream>>>(Xn, rowrange, csr, aggb);
  aggregate_np<<<NP_BLOCKS, 256, 0, stream>>>(x_pod, x_node, cnt_src, rowrange, csr, aggb);
  gemm_fused<<<768, 256, 0, stream>>>((const unsigned short*)aggb, Wt, Wt2,
                                      b_call, b_in, b_ni, b_ls, b_ln, b_lp, out);
}